// Round 7
// baseline (92.594 us; speedup 1.0000x reference)
//
#include <hip/hip_runtime.h>
#include <math.h>

// Fused kernel, 512 blocks (256 point-groups x 2 face-halves), all co-resident
// at 2 blocks/CU (32 waves/CU -> 8 waves/SIMD: the R5 probe showed the hot
// loop needs 8 waves/SIMD; R6's 256-block version ran at 4 and cost 2x).
// Cross-block combine via device-scope atomicAdd into out (zeroed by
// hipMemsetAsync). Slow pairs: per-lane 32-bit mask, replayed after the hot
// loop by the owning lane (no LDS list, no atomics, no in-loop call).

namespace {
constexpr int kNpts = 32 * 32 * 32;   // 32768 frequency points
constexpr int kHalf = kNpts / 2;      // 16384 conj-unique points
constexpr int kNF = 1024;             // faces
constexpr int kThreads = 1024;        // 16 waves
constexpr int kWaves = 16;
constexpr int kFaceHalves = 2;
constexpr int kFPW = (kNF / kFaceHalves) / kWaves;   // 32 faces per wave
constexpr int kBlocks = (kHalf / 64) * kFaceHalves;  // 512 blocks
}

__device__ __forceinline__ float fract32(float x) {
#if __has_builtin(__builtin_amdgcn_fractf)
    return __builtin_amdgcn_fractf(x);
#else
    return x - floorf(x);
#endif
}

// exact f64 replica of the reference's pair case value
__device__ __forceinline__ void pair_case_f64(double x1, double x2, double x3,
                                              double& vr, double& vi) {
    const double m = (x1 + x2) * 0.5;
    const double d = m - x3;
    double sm, cm, s3, c3;
    sincos(m, &sm, &cm);
    sincos(x3, &s3, &c3);
    vr = (sm + (cm - c3) / d) / d;
    vi = (cm + (s3 - sm) / d) / d;
}

// Exact f64 replica of the reference region logic for one (face, point) pair.
// __noinline__ and called only AFTER the hot loop, so its register usage does
// not constrain the hot loop's allocation.
__device__ __noinline__ void slow_exact(
        int f, int p, const float* __restrict__ verts,
        const float* __restrict__ box, const int* __restrict__ faces,
        const float* __restrict__ xi0, const float* __restrict__ xi1,
        const float* __restrict__ xi2, float& cr, float& ci) {
    const double SEPS = __builtin_sqrt(1.19209e-07);  // matches float(np.sqrt(EPS))
    const double TWO_PI = 6.283185307179586;
    const double INV_TWO_PI = 0.15915494309189535;

    const int i2 = p & 31, i1 = (p >> 5) & 31, i0 = p >> 10;
    const double xxd = (double)xi0[i0] * INV_TWO_PI;
    const double xyd = (double)xi1[i1] * INV_TWO_PI;
    const double xzd = (double)xi2[i2] * INV_TWO_PI;
    const double lo0 = (double)box[0], lo1 = (double)box[2], lo2 = (double)box[4];
    const int ia = faces[3 * f + 0], ib = faces[3 * f + 1], ic = faces[3 * f + 2];
    const double ax = (double)verts[3 * ia + 0] - lo0, ay = (double)verts[3 * ia + 1] - lo1, az = (double)verts[3 * ia + 2] - lo2;
    const double bx = (double)verts[3 * ib + 0] - lo0, by = (double)verts[3 * ib + 1] - lo1, bz = (double)verts[3 * ib + 2] - lo2;
    const double cx = (double)verts[3 * ic + 0] - lo0, cy = (double)verts[3 * ic + 1] - lo1, cz = (double)verts[3 * ic + 2] - lo2;
    // f32 area exactly as the fast-path prep computes it
    const float axf = (float)ax, ayf = (float)ay, azf = (float)az;
    const float bxf = (float)bx, byf = (float)by, bzf = (float)bz;
    const float cxf = (float)cx, cyf = (float)cy, czf = (float)cz;
    const float e1x = bxf - axf, e1y = byf - ayf, e1z = bzf - azf;
    const float e2x = cxf - axf, e2y = cyf - ayf, e2z = czf - azf;
    const float crx = e1y * e2z - e1z * e2y;
    const float cry = e1z * e2x - e1x * e2z;
    const float crz = e1x * e2y - e1y * e2x;
    const float areaf = 0.5f * sqrtf(crx * crx + cry * cry + crz * crz);
    const double rad = fma(xzd, az, fma(xyd, ay, xxd * ax));
    const double rbd = fma(xzd, bz, fma(xyd, by, xxd * bx));
    const double rcd = fma(xzd, cz, fma(xyd, cy, xxd * cx));
    const double xa = rad * TWO_PI, xb = rbd * TWO_PI, xc = rcd * TWO_PI;
    const double dAB = xb - xa, dBC = xc - xb, dCA = xa - xc;
    const double aab = fabs(dAB), abc = fabs(dBC), aca = fabs(dCA);
    const bool s2 = aab < SEPS, s3 = abc < SEPS, s4 = aca < SEPS;
    const bool c2 = aab <= SEPS, c3 = abc <= SEPS, c4 = aca <= SEPS;
    const bool R1 = (s2 && s3) || (s3 && s4) || (s4 && s2);
    const bool R2 = c2 && !R1;
    const bool R3b = c3 && !R2 && !R1;
    const bool R4 = c4 && !R3b && !R2 && !R1;
    double vr, vi;
    if (R1) {
        const double m = ((xa + xb) + xc) / 3.0;
        double sm, cm;
        sincos(m, &sm, &cm);
        vr = cm / 2.0;
        vi = -sm / 2.0;
    } else if (R2) {
        pair_case_f64(xa, xb, xc, vr, vi);
    } else if (R3b) {
        pair_case_f64(xb, xc, xa, vr, vi);
    } else if (R4) {
        pair_case_f64(xc, xa, xb, vr, vi);
    } else {
        double sa, ca, sb, cb, sc, cc;
        sincos(xa, &sa, &ca);
        sincos(xb, &sb, &cb);
        sincos(xc, &sc, &cc);
        const double da = dAB * dCA, db = dBC * dAB, dc = dCA * dBC;
        vr = (ca / da + cb / db) + cc / dc;
        vi = -((sa / da + sb / db) + sc / dc);
    }
    cr = areaf * (float)vr;
    ci = areaf * (float)vi;
}

__global__ __launch_bounds__(kThreads, 8) void fourier_all(
        const float* __restrict__ verts, const float* __restrict__ box,
        const int* __restrict__ faces, const float* __restrict__ xi0,
        const float* __restrict__ xi1, const float* __restrict__ xi2,
        float* __restrict__ out, int interleaved) {
    const float INV_TWO_PI_F = 0.15915494f;
    const float TAUP_REV2 = 2.5330296e-5f;  // 1e-3 rad^2 in rev^2 (product gate)

    __shared__ float4 rec[kNF / kFaceHalves][3];  // 24 KB: this half's faces
    __shared__ float accR[kWaves][64];            // 4 KB
    __shared__ float accI[kWaves][64];            // 4 KB
    __shared__ float wsum[kWaves];
    __shared__ float meshar_sh;

    const int t = threadIdx.x;
    const int l = t & 63;                 // lane -> point within group
    const int w = t >> 6;                 // wave -> face subgroup
    const int pb = blockIdx.x & 255;      // point group [0,256)
    const int fh = blockIdx.x >> 8;       // face half

    // ---- prep: thread t computes face t's coords+area (ALL 1024 faces, for
    // meshar); records coords only for this block's face half ----
    {
        const int f = t;
        const float lo0 = box[0], lo1 = box[2], lo2 = box[4];
        const int ia = faces[3 * f + 0], ib = faces[3 * f + 1], ic = faces[3 * f + 2];
        const float ax = verts[3 * ia + 0] - lo0, ay = verts[3 * ia + 1] - lo1, az = verts[3 * ia + 2] - lo2;
        const float bx = verts[3 * ib + 0] - lo0, by = verts[3 * ib + 1] - lo1, bz = verts[3 * ib + 2] - lo2;
        const float cx = verts[3 * ic + 0] - lo0, cy = verts[3 * ic + 1] - lo1, cz = verts[3 * ic + 2] - lo2;
        const float e1x = bx - ax, e1y = by - ay, e1z = bz - az;
        const float e2x = cx - ax, e2y = cy - ay, e2z = cz - az;
        const float crx = e1y * e2z - e1z * e2y;
        const float cry = e1z * e2x - e1x * e2z;
        const float crz = e1x * e2y - e1y * e2x;
        const float area = 0.5f * sqrtf(crx * crx + cry * cry + crz * crz);
        if ((f >> 9) == fh) {
            const int r = f & 511;
            rec[r][0] = make_float4(ax, ay, az, bx);
            rec[r][1] = make_float4(by, bz, cx, cy);
            rec[r][2] = make_float4(cz, area * 0.025330296f, 0.0f, 0.0f);
        }
        // wave-reduce area over all 16 waves -> meshar
        float a = area;
        a += __shfl_down(a, 32, 64);
        a += __shfl_down(a, 16, 64);
        a += __shfl_down(a, 8, 64);
        a += __shfl_down(a, 4, 64);
        a += __shfl_down(a, 2, 64);
        a += __shfl_down(a, 1, 64);
        if (l == 0) wsum[w] = a;
    }
    __syncthreads();
    if (t == 0) {
        float s = wsum[0];
#pragma unroll
        for (int j = 1; j < kWaves; ++j) s += wsum[j];
        meshar_sh = s;
    }

    // ---- main loop: wave w sums its 32 faces for point p; slow pairs go to
    // a per-lane bitmask (kFPW == 32), replayed after the loop ----
    const int p = pb * 64 + l;            // p in [0, kHalf)
    const int i2 = p & 31, i1 = (p >> 5) & 31, i0 = p >> 10;
    const float xxr = xi0[i0] * INV_TWO_PI_F;
    const float xyr = xi1[i1] * INV_TWO_PI_F;
    const float xzr = xi2[i2] * INV_TWO_PI_F;

    float re = 0.0f, im = 0.0f;
    unsigned slowMask = 0u;
    const int rbase = w * kFPW;

#pragma unroll 4
    for (int i = 0; i < kFPW; ++i) {
        const float4 q0 = rec[rbase + i][0];
        const float4 q1 = rec[rbase + i][1];
        const float4 q2 = rec[rbase + i][2];
        // phases in revolutions, f32 (F has O(1) derivatives; f32 phase noise
        // -> ~1e-5-level output error; denominators gated below)
        const float ra = fmaf(xzr, q0.z, fmaf(xyr, q0.y, xxr * q0.x));
        const float rb = fmaf(xzr, q1.y, fmaf(xyr, q1.x, xxr * q0.w));
        const float rc = fmaf(xzr, q2.x, fmaf(xyr, q1.w, xxr * q1.z));
        const float fdab = rb - ra, fdbc = rc - rb, fdca = ra - rc;
        const float d1 = fdab * fdca;   // rev^2 pair products (product gate)
        const float d2 = fdbc * fdab;
        const float d3 = fdca * fdbc;
        const float mn = fminf(fminf(fabsf(d1), fabsf(d2)), fabsf(d3));
        if (mn > TAUP_REV2) {
            // fast path: v_fract -> hw v_sin/v_cos (rev input), 1 rcp;
            // area/(4pi^2) folded into the reciprocal
            const float R3w = __builtin_amdgcn_rcpf(d1 * fdbc) * q2.y;
            const float r1 = fdbc * R3w, r2 = fdca * R3w, r3 = fdab * R3w;
            const float fa = fract32(ra);
            const float fb = fract32(rb);
            const float fc = fract32(rc);
            const float sa = __builtin_amdgcn_sinf(fa), ca = __builtin_amdgcn_cosf(fa);
            const float sb = __builtin_amdgcn_sinf(fb), cb = __builtin_amdgcn_cosf(fb);
            const float sc = __builtin_amdgcn_sinf(fc), cc = __builtin_amdgcn_cosf(fc);
            re = fmaf(cc, r3, fmaf(cb, r2, fmaf(ca, r1, re)));
            im = fmaf(-sc, r3, fmaf(-sb, r2, fmaf(-sa, r1, im)));
        } else {
            slowMask |= (1u << i);
        }
    }

    // ---- per-lane replay of this lane's slow pairs (rare; exact f64) ----
    if (slowMask) {
        const int gbase = fh * 512 + rbase;
        unsigned m = slowMask;
        do {
            const int i = __builtin_ctz(m);
            m &= m - 1u;
            float cr, ci;
            slow_exact(gbase + i, p, verts, box, faces, xi0, xi1, xi2, cr, ci);
            re += cr;
            im += ci;
        } while (m);
    }

    accR[w][l] = re;
    accI[w][l] = im;
    __syncthreads();

    // ---- reduce 16 wave partials, scale, atomic-add final contribution ----
    if (t < 64) {
        float R = accR[0][l], I = accI[0][l];
#pragma unroll
        for (int g = 1; g < kWaves; ++g) { R += accR[g][l]; I += accI[g][l]; }
        const float inv2 = 2.0f / meshar_sh;
        R *= inv2;
        I *= inv2;
        const int q = kNpts - 1 - p;
        if (interleaved) {
            atomicAdd(&out[2 * p + 0], R);
            atomicAdd(&out[2 * p + 1], I);
            atomicAdd(&out[2 * q + 0], R);
            atomicAdd(&out[2 * q + 1], -I);
        } else {
            atomicAdd(&out[p], R);
            atomicAdd(&out[q], R);
        }
    }
}

extern "C" void kernel_launch(void* const* d_in, const int* in_sizes, int n_in,
                              void* d_out, int out_size, void* d_ws, size_t ws_size,
                              hipStream_t stream) {
    const float* verts = (const float*)d_in[0];
    const float* box   = (const float*)d_in[1];
    const float* xi0v  = (const float*)d_in[2];
    const float* xi1v  = (const float*)d_in[3];
    const float* xi2v  = (const float*)d_in[4];
    const int*   faces = (const int*)d_in[5];
    (void)d_ws; (void)ws_size;

    const int interleaved = (out_size == 2 * kNpts) ? 1 : 0;

    hipMemsetAsync(d_out, 0, (size_t)out_size * sizeof(float), stream);
    hipLaunchKernelGGL(fourier_all, dim3(kBlocks), dim3(kThreads), 0, stream,
                       verts, box, faces, xi0v, xi1v, xi2v,
                       (float*)d_out, interleaved);
}